// Round 16
// baseline (29.990 us; speedup 1.0000x reference)
//
#include <hip/hip_runtime.h>
#include <math.h>
#include <stdint.h>

namespace {

constexpr int kB = 16384;
constexpr int kN = 12;
constexpr int kD = 64;
constexpr int kL = 2;
constexpr int kH = kN * kD;          // 768
constexpr float kEps = 1e-5f;

constexpr int BLOCK = 512;           // 8 waves/block
constexpr int GRID  = kB / 32;       // 512 blocks: 4 graphs/wave, 2 blocks/CU

// LDS map (uint32 units): [0,4096) W-f16, [4096,5632) cls-f16, [5632,6784) qpu
constexpr int LDS_U32 = 5632 + 8 * 4 * 36;   // 6784 -> 27.1 KB

typedef _Float16 half2v __attribute__((ext_vector_type(2)));
typedef float f32x2 __attribute__((ext_vector_type(2)));

__device__ __forceinline__ uint32_t pack_f16(float a, float b) {
    auto p = __builtin_amdgcn_cvt_pkrtz(a, b);
    return __builtin_bit_cast(uint32_t, p);
}
__device__ __forceinline__ float fdot2(uint32_t a, uint32_t b, float c) {
    return __builtin_amdgcn_fdot2(__builtin_bit_cast(half2v, a),
                                  __builtin_bit_cast(half2v, b), c, false);
}
// Native v2f32 fma -> v_pk_fma_f32 (r15-proven; hand-written v_pk_* asm is
// banned: r14 mis-encoded).
__device__ __forceinline__ f32x2 vfma(f32x2 a, f32x2 b, f32x2 c) {
    return __builtin_elementwise_fma(a, b, c);
}

// x += row_ror:N of x (16-lane DPP row). Builtin form (r10/r13/r15-proven).
template<int N>
__device__ __forceinline__ float dpp_ror_add(float x) {
    int r = __builtin_amdgcn_update_dpp(0, __builtin_bit_cast(int, x),
                                        0x120 + N, 0xF, 0xF, true);
    return x + __builtin_bit_cast(float, r);
}
__device__ __forceinline__ float rowSum16(float x) {
    x = dpp_ror_add<8>(x);
    x = dpp_ror_add<4>(x);
    x = dpp_ror_add<2>(x);
    x = dpp_ror_add<1>(x);
    return x;
}

__global__ __launch_bounds__(BLOCK, 4)
void gnn_fused(const float* __restrict__ x,
               const float* __restrict__ mp_w,
               const float* __restrict__ mp_b,
               const float* __restrict__ attn_w,
               const float* __restrict__ ln_g,
               const float* __restrict__ ln_b,
               const float* __restrict__ cls_w,
               const float* __restrict__ cls_b,
               float* __restrict__ out)
{
    __shared__ __align__(16) uint32_t lds[LDS_U32];

    const int tid  = threadIdx.x;
    const int lane = tid & 63;
    const int wid  = tid >> 6;           // 0..7
    const int grp  = lane >> 4;          // graph slot (DPP row)
    const int sub  = lane & 15;          // owns feats 4sub..4sub+3
    const int e0   = 4 * sub;
    const int b    = (blockIdx.x * 8 + wid) * 4 + grp;

    // ---- issue x loads first (overlap with table staging) ----
    f32x2 hA[kN], hB[kN];                // feats {e0,e0+1} / {e0+2,e0+3}
    const float* xb = x + b * kH + e0;
#pragma unroll
    for (int n = 0; n < kN; ++n) {
        const float4 t = *(const float4*)(xb + n * kD);
        hA[n] = f32x2{t.x, t.y};
        hB[n] = f32x2{t.z, t.w};
    }

    // ---- stage W f16 table: 2048 uint2 entries (r13-proven bounds; now
    //      amortized over 8 waves).  Entry i = ld4*64 + e, ld4 = l*16+d4:
    //      lds[i*2+{0,1}] = { h2(W[4d4][e],W[4d4+1][e]), h2(W[4d4+2][e],W[4d4+3][e]) },
    //      W[d][e] = mp_w[l][e][d]. Lanes vary e fastest -> conflict-free. ----
#pragma unroll
    for (int it = 0; it < 4; ++it) {
        const int i   = tid + it * BLOCK;    // 0..2047 (entry index)
        const int e   = i & 63;
        const int ld4 = i >> 6;              // 0..31 = l*16 + d4
        const int l   = ld4 >> 4;
        const int d4  = ld4 & 15;
        const float4 w = *(const float4*)&mp_w[(l * kD + e) * kD + 4 * d4];
        uint2 pk;
        pk.x = pack_f16(w.x, w.y);
        pk.y = pack_f16(w.z, w.w);
        *(uint2*)&lds[i * 2] = pk;
    }
    // ---- stage cls f16 table: lds[4096 + k], k = n*128 + j*4 + c ----
#pragma unroll
    for (int it = 0; it < 3; ++it) {
        const int k = tid + it * BLOCK;      // 0..1535
        const int c = k & 3;
        const int j = (k >> 2) & 31;
        const int n = k >> 7;
        const float2 w = *(const float2*)&cls_w[c * kH + n * kD + 2 * j];
        lds[4096 + k] = pack_f16(w.x, w.y);
    }
    __syncthreads();

    uint32_t* qrow = &lds[5632 + (wid * 4 + grp) * 36];

    const f32x2 kA2v = {2.3022081f, 2.3022081f};   // 2*log2e*0.79788456
    const f32x2 kB2v = {0.1029440f, 0.1029440f};   // kA2v*0.044715

#pragma unroll
    for (int l = 0; l < kL; ++l) {
        // w2 pre-scaled by log2e -> exp2 direct (w1 + attn_b cancel in softmax)
        const float4 w2r = *(const float4*)&attn_w[l * (2 * kD) + kD + e0];
        const f32x2 w2a = {w2r.x * 1.44269504f, w2r.y * 1.44269504f};
        const f32x2 w2b = {w2r.z * 1.44269504f, w2r.w * 1.44269504f};

        // ---- ej -> exp2 -> sum & q, fused (|ej| <~ 1: no max subtraction) ----
        float sum = 0.f;
        f32x2 qA = {0.f, 0.f}, qB = {0.f, 0.f};
#pragma unroll
        for (int n = 0; n < kN; ++n) {
            const f32x2 v2 = vfma(hB[n], w2b, hA[n] * w2a);
            float v = v2.x + v2.y;
            v = rowSum16(v);
            const float sn = __builtin_amdgcn_exp2f(v);
            sum += sn;
            const f32x2 sn2 = {sn, sn};
            qA = vfma(sn2, hA[n], qA);
            qB = vfma(sn2, hB[n], qB);
        }
        const float inv = __builtin_amdgcn_rcpf(sum);

        uint2 qp;
        qp.x = pack_f16(qA.x, qA.y);
        qp.y = pack_f16(qB.x, qB.y);
        *(uint2*)&qrow[2 * sub] = qp;
        __builtin_amdgcn_wave_barrier();   // same-wave LDS RAW, lgkmcnt-ordered

        // ---- agg[e] = inv * sum_d q[d] W[d][e] + mp_b[e]; lane owns e0..e0+3
        float c0 = 0.f, c1 = 0.f, c2 = 0.f, c3 = 0.f;
        const uint32_t* wlane = &lds[l * 2048 + 8 * sub];
#pragma unroll
        for (int d8 = 0; d8 < 8; ++d8) {
            const uint4 qv = *(const uint4*)&qrow[4 * d8];   // feats 8d8..8d8+7
            {
                const uint4 r0 = *(const uint4*)&wlane[(2 * d8) * 128];
                const uint4 r1 = *(const uint4*)&wlane[(2 * d8) * 128 + 4];
                c0 = fdot2(qv.x, r0.x, c0); c0 = fdot2(qv.y, r0.y, c0);
                c1 = fdot2(qv.x, r0.z, c1); c1 = fdot2(qv.y, r0.w, c1);
                c2 = fdot2(qv.x, r1.x, c2); c2 = fdot2(qv.y, r1.y, c2);
                c3 = fdot2(qv.x, r1.z, c3); c3 = fdot2(qv.y, r1.w, c3);
            }
            {
                const uint4 r0 = *(const uint4*)&wlane[(2 * d8 + 1) * 128];
                const uint4 r1 = *(const uint4*)&wlane[(2 * d8 + 1) * 128 + 4];
                c0 = fdot2(qv.z, r0.x, c0); c0 = fdot2(qv.w, r0.y, c0);
                c1 = fdot2(qv.z, r0.z, c1); c1 = fdot2(qv.w, r0.w, c1);
                c2 = fdot2(qv.z, r1.x, c2); c2 = fdot2(qv.w, r1.y, c2);
                c3 = fdot2(qv.z, r1.z, c3); c3 = fdot2(qv.w, r1.w, c3);
            }
        }
        const float4 mb4 = *(const float4*)&mp_b[l * kD + e0];
        const f32x2 ccA = {fmaf(c0, inv, mb4.x), fmaf(c1, inv, mb4.y)};
        const f32x2 ccB = {fmaf(c2, inv, mb4.z), fmaf(c3, inv, mb4.w)};

        const float4 g4 = *(const float4*)&ln_g[l * kD + e0];
        const float4 b4 = *(const float4*)&ln_b[l * kD + e0];
        const f32x2 g01 = {g4.x, g4.y}, g23 = {g4.z, g4.w};
        const f32x2 b01 = {b4.x, b4.y}, b23 = {b4.z, b4.w};

        // ---- residual + GELU + LayerNorm on v2f32 (r15-proven packed form).
        //      ge = a - a*rcp(exp2(a(kA+kB a^2))+1) ----
#pragma unroll
        for (int n = 0; n < kN; ++n) {
            const f32x2 aa  = hA[n] + ccA;
            const f32x2 ab  = hB[n] + ccB;
            const f32x2 ta  = vfma(aa * aa, kB2v, kA2v);
            const f32x2 tb  = vfma(ab * ab, kB2v, kA2v);
            const f32x2 ua  = aa * ta;
            const f32x2 ub  = ab * tb;
            const f32x2 ra  = {__builtin_amdgcn_rcpf(__builtin_amdgcn_exp2f(ua.x) + 1.f),
                               __builtin_amdgcn_rcpf(__builtin_amdgcn_exp2f(ua.y) + 1.f)};
            const f32x2 rb  = {__builtin_amdgcn_rcpf(__builtin_amdgcn_exp2f(ub.x) + 1.f),
                               __builtin_amdgcn_rcpf(__builtin_amdgcn_exp2f(ub.y) + 1.f)};
            const f32x2 geA = vfma(aa, -ra, aa);
            const f32x2 geB = vfma(ab, -rb, ab);

            const f32x2 sp = geA + geB;
            const f32x2 s2p = vfma(geB, geB, geA * geA);
            float s1 = rowSum16(sp.x + sp.y);
            float s2 = rowSum16(s2p.x + s2p.y);
            const float mu  = s1 * (1.f / 64.f);
            const float var = fmaf(s2, 1.f / 64.f, -(mu * mu));
            const float rs  = __builtin_amdgcn_rsqf(var + kEps);
            const f32x2 rs2 = {rs, rs};
            const f32x2 mm  = {-mu, -mu};
            hA[n] = vfma(geA + mm, rs2 * g01, b01);
            hB[n] = vfma(geB + mm, rs2 * g23, b23);
        }
    }

    // ---- classifier (f16 cls from LDS, offset-immediate reads) ----
    float p0 = 0.f, p1 = 0.f, p2 = 0.f, p3 = 0.f;
    const uint32_t* clane = &lds[4096 + 8 * sub];
#pragma unroll
    for (int n = 0; n < kN; ++n) {
        const uint32_t hp0 = pack_f16(hA[n].x, hA[n].y);
        const uint32_t hp1 = pack_f16(hB[n].x, hB[n].y);
        const uint4 cv0 = *(const uint4*)&clane[n * 128];      // j=2sub,   c=0..3
        const uint4 cv1 = *(const uint4*)&clane[n * 128 + 4];  // j=2sub+1, c=0..3
        p0 = fdot2(hp0, cv0.x, p0); p0 = fdot2(hp1, cv1.x, p0);
        p1 = fdot2(hp0, cv0.y, p1); p1 = fdot2(hp1, cv1.y, p1);
        p2 = fdot2(hp0, cv0.z, p2); p2 = fdot2(hp1, cv1.z, p2);
        p3 = fdot2(hp0, cv0.w, p3); p3 = fdot2(hp1, cv1.w, p3);
    }
    p0 = rowSum16(p0);
    p1 = rowSum16(p1);
    p2 = rowSum16(p2);
    p3 = rowSum16(p3);

    if (sub == 0) {
        const float4 cbv = *(const float4*)cls_b;
        *(float4*)&out[b * 4] = make_float4(p0 + cbv.x, p1 + cbv.y,
                                            p2 + cbv.z, p3 + cbv.w);
    }
}

} // namespace

extern "C" void kernel_launch(void* const* d_in, const int* in_sizes, int n_in,
                              void* d_out, int out_size, void* d_ws, size_t ws_size,
                              hipStream_t stream)
{
    const float* x      = (const float*)d_in[0];
    const float* mp_w   = (const float*)d_in[1];
    const float* mp_b   = (const float*)d_in[2];
    const float* attn_w = (const float*)d_in[3];
    // d_in[4] = attn_b : cancels in softmax, unused
    const float* ln_g   = (const float*)d_in[5];
    const float* ln_b   = (const float*)d_in[6];
    const float* cls_w  = (const float*)d_in[7];
    const float* cls_b  = (const float*)d_in[8];
    float* out = (float*)d_out;

    gnn_fused<<<GRID, BLOCK, 0, stream>>>(x, mp_w, mp_b, attn_w,
                                          ln_g, ln_b, cls_w, cls_b, out);
}

// Round 17
// 27.559 us; speedup vs baseline: 1.0882x; 1.0882x over previous
//
#include <hip/hip_runtime.h>
#include <math.h>
#include <stdint.h>

namespace {

constexpr int kB = 16384;
constexpr int kN = 12;
constexpr int kD = 64;
constexpr int kL = 2;
constexpr int kH = kN * kD;          // 768
constexpr float kEps = 1e-5f;

constexpr int BLOCK = 256;           // 4 waves (r16: 512 regressed -8%, reverted)
constexpr int GRID  = kB / 16;       // 1024 blocks: 4 graphs/wave, 4 blocks/CU

// LDS map (uint32 units): [0,4096) W-f16, [4096,5632) cls-f16, [5632,6208) qpu
constexpr int LDS_U32 = 5632 + 4 * 4 * 36;   // 6208 -> 24.8 KB

typedef _Float16 half2v __attribute__((ext_vector_type(2)));
typedef float f32x2 __attribute__((ext_vector_type(2)));

__device__ __forceinline__ uint32_t pack_f16(float a, float b) {
    auto p = __builtin_amdgcn_cvt_pkrtz(a, b);
    return __builtin_bit_cast(uint32_t, p);
}
__device__ __forceinline__ float fdot2(uint32_t a, uint32_t b, float c) {
    return __builtin_amdgcn_fdot2(__builtin_bit_cast(half2v, a),
                                  __builtin_bit_cast(half2v, b), c, false);
}
// Native v2f32 fma -> v_pk_fma_f32 (r15-proven; hand-written v_pk_* asm is
// banned: r14 mis-encoded).
__device__ __forceinline__ f32x2 vfma(f32x2 a, f32x2 b, f32x2 c) {
    return __builtin_elementwise_fma(a, b, c);
}

// x += row_ror:N of x (16-lane DPP row). Builtin form (r10/r13/r15-proven).
template<int N>
__device__ __forceinline__ float dpp_ror_add(float x) {
    int r = __builtin_amdgcn_update_dpp(0, __builtin_bit_cast(int, x),
                                        0x120 + N, 0xF, 0xF, true);
    return x + __builtin_bit_cast(float, r);
}
__device__ __forceinline__ float rowSum16(float x) {
    x = dpp_ror_add<8>(x);
    x = dpp_ror_add<4>(x);
    x = dpp_ror_add<2>(x);
    x = dpp_ror_add<1>(x);
    return x;
}

__global__ __launch_bounds__(BLOCK, 4)
void gnn_fused(const float* __restrict__ x,
               const float* __restrict__ mp_w,
               const float* __restrict__ mp_b,
               const float* __restrict__ attn_w,
               const float* __restrict__ ln_g,
               const float* __restrict__ ln_b,
               const float* __restrict__ cls_w,
               const float* __restrict__ cls_b,
               float* __restrict__ out)
{
    __shared__ __align__(16) uint32_t lds[LDS_U32];

    const int tid  = threadIdx.x;
    const int lane = tid & 63;
    const int wid  = tid >> 6;
    const int grp  = lane >> 4;          // graph slot (DPP row)
    const int sub  = lane & 15;          // owns feats 4sub..4sub+3
    const int e0   = 4 * sub;
    const int b    = (blockIdx.x * 4 + wid) * 4 + grp;

    // ---- issue x loads first (overlap with table staging) ----
    f32x2 hA[kN], hB[kN];                // feats {e0,e0+1} / {e0+2,e0+3}
    const float* xb = x + b * kH + e0;
#pragma unroll
    for (int n = 0; n < kN; ++n) {
        const float4 t = *(const float4*)(xb + n * kD);
        hA[n] = f32x2{t.x, t.y};
        hB[n] = f32x2{t.z, t.w};
    }

    // ---- stage W f16 table: 2048 uint2 entries (r13-proven bounds).
    //      Entry i = ld4*64 + e, ld4 = l*16+d4 in [0,32):
    //      lds[i*2+{0,1}] = { h2(W[4d4][e],W[4d4+1][e]), h2(W[4d4+2][e],W[4d4+3][e]) },
    //      W[d][e] = mp_w[l][e][d]. Lanes vary e fastest -> conflict-free. ----
#pragma unroll
    for (int it = 0; it < 8; ++it) {
        const int i   = tid + it * BLOCK;    // 0..2047 (entry index)
        const int e   = i & 63;
        const int ld4 = i >> 6;              // 0..31 = l*16 + d4
        const int l   = ld4 >> 4;
        const int d4  = ld4 & 15;
        const float4 w = *(const float4*)&mp_w[(l * kD + e) * kD + 4 * d4];
        uint2 pk;
        pk.x = pack_f16(w.x, w.y);
        pk.y = pack_f16(w.z, w.w);
        *(uint2*)&lds[i * 2] = pk;
    }
    // ---- stage cls f16 table: lds[4096 + k], k = n*128 + j*4 + c ----
#pragma unroll
    for (int it = 0; it < 6; ++it) {
        const int k = tid + it * BLOCK;      // 0..1535
        const int c = k & 3;
        const int j = (k >> 2) & 31;
        const int n = k >> 7;
        const float2 w = *(const float2*)&cls_w[c * kH + n * kD + 2 * j];
        lds[4096 + k] = pack_f16(w.x, w.y);
    }
    __syncthreads();

    uint32_t* qrow = &lds[5632 + (wid * 4 + grp) * 36];

    const f32x2 kA2v = {2.3022081f, 2.3022081f};   // 2*log2e*0.79788456
    const f32x2 kB2v = {0.1029440f, 0.1029440f};   // kA2v*0.044715

#pragma unroll
    for (int l = 0; l < kL; ++l) {
        // w2 pre-scaled by log2e -> exp2 direct (w1 + attn_b cancel in softmax)
        const float4 w2r = *(const float4*)&attn_w[l * (2 * kD) + kD + e0];
        const f32x2 w2a = {w2r.x * 1.44269504f, w2r.y * 1.44269504f};
        const f32x2 w2b = {w2r.z * 1.44269504f, w2r.w * 1.44269504f};

        // ---- ej -> exp2 -> sum & q, fused (|ej| <~ 1: no max subtraction) ----
        float sum = 0.f;
        f32x2 qA = {0.f, 0.f}, qB = {0.f, 0.f};
#pragma unroll
        for (int n = 0; n < kN; ++n) {
            const f32x2 v2 = vfma(hB[n], w2b, hA[n] * w2a);
            float v = v2.x + v2.y;
            v = rowSum16(v);
            const float sn = __builtin_amdgcn_exp2f(v);
            sum += sn;
            const f32x2 sn2 = {sn, sn};
            qA = vfma(sn2, hA[n], qA);
            qB = vfma(sn2, hB[n], qB);
        }
        const float inv = __builtin_amdgcn_rcpf(sum);

        uint2 qp;
        qp.x = pack_f16(qA.x, qA.y);
        qp.y = pack_f16(qB.x, qB.y);
        *(uint2*)&qrow[2 * sub] = qp;
        __builtin_amdgcn_wave_barrier();   // same-wave LDS RAW, lgkmcnt-ordered

        // ---- agg[e] = inv * sum_d q[d] W[d][e] + mp_b[e]; lane owns e0..e0+3
        float c0 = 0.f, c1 = 0.f, c2 = 0.f, c3 = 0.f;
        const uint32_t* wlane = &lds[l * 2048 + 8 * sub];
#pragma unroll
        for (int d8 = 0; d8 < 8; ++d8) {
            const uint4 qv = *(const uint4*)&qrow[4 * d8];   // feats 8d8..8d8+7
            {
                const uint4 r0 = *(const uint4*)&wlane[(2 * d8) * 128];
                const uint4 r1 = *(const uint4*)&wlane[(2 * d8) * 128 + 4];
                c0 = fdot2(qv.x, r0.x, c0); c0 = fdot2(qv.y, r0.y, c0);
                c1 = fdot2(qv.x, r0.z, c1); c1 = fdot2(qv.y, r0.w, c1);
                c2 = fdot2(qv.x, r1.x, c2); c2 = fdot2(qv.y, r1.y, c2);
                c3 = fdot2(qv.x, r1.z, c3); c3 = fdot2(qv.y, r1.w, c3);
            }
            {
                const uint4 r0 = *(const uint4*)&wlane[(2 * d8 + 1) * 128];
                const uint4 r1 = *(const uint4*)&wlane[(2 * d8 + 1) * 128 + 4];
                c0 = fdot2(qv.z, r0.x, c0); c0 = fdot2(qv.w, r0.y, c0);
                c1 = fdot2(qv.z, r0.z, c1); c1 = fdot2(qv.w, r0.w, c1);
                c2 = fdot2(qv.z, r1.x, c2); c2 = fdot2(qv.w, r1.y, c2);
                c3 = fdot2(qv.z, r1.z, c3); c3 = fdot2(qv.w, r1.w, c3);
            }
        }
        const float4 mb4 = *(const float4*)&mp_b[l * kD + e0];
        const f32x2 ccA = {fmaf(c0, inv, mb4.x), fmaf(c1, inv, mb4.y)};
        const f32x2 ccB = {fmaf(c2, inv, mb4.z), fmaf(c3, inv, mb4.w)};

        const float4 g4 = *(const float4*)&ln_g[l * kD + e0];
        const float4 b4 = *(const float4*)&ln_b[l * kD + e0];
        const f32x2 g01 = {g4.x, g4.y}, g23 = {g4.z, g4.w};
        const f32x2 b01 = {b4.x, b4.y}, b23 = {b4.z, b4.w};

        // ---- residual + GELU + LayerNorm on v2f32 (r15-proven packed form).
        //      ge = a - a*rcp(exp2(a(kA+kB a^2))+1) ----
#pragma unroll
        for (int n = 0; n < kN; ++n) {
            const f32x2 aa  = hA[n] + ccA;
            const f32x2 ab  = hB[n] + ccB;
            const f32x2 ta  = vfma(aa * aa, kB2v, kA2v);
            const f32x2 tb  = vfma(ab * ab, kB2v, kA2v);
            const f32x2 ua  = aa * ta;
            const f32x2 ub  = ab * tb;
            const f32x2 ra  = {__builtin_amdgcn_rcpf(__builtin_amdgcn_exp2f(ua.x) + 1.f),
                               __builtin_amdgcn_rcpf(__builtin_amdgcn_exp2f(ua.y) + 1.f)};
            const f32x2 rb  = {__builtin_amdgcn_rcpf(__builtin_amdgcn_exp2f(ub.x) + 1.f),
                               __builtin_amdgcn_rcpf(__builtin_amdgcn_exp2f(ub.y) + 1.f)};
            const f32x2 geA = vfma(aa, -ra, aa);
            const f32x2 geB = vfma(ab, -rb, ab);

            const f32x2 sp = geA + geB;
            const f32x2 s2p = vfma(geB, geB, geA * geA);
            float s1 = rowSum16(sp.x + sp.y);
            float s2 = rowSum16(s2p.x + s2p.y);
            const float mu  = s1 * (1.f / 64.f);
            const float var = fmaf(s2, 1.f / 64.f, -(mu * mu));
            const float rs  = __builtin_amdgcn_rsqf(var + kEps);
            const f32x2 rs2 = {rs, rs};
            const f32x2 mm  = {-mu, -mu};
            hA[n] = vfma(geA + mm, rs2 * g01, b01);
            hB[n] = vfma(geB + mm, rs2 * g23, b23);
        }
    }

    // ---- classifier (f16 cls from LDS, offset-immediate reads) ----
    float p0 = 0.f, p1 = 0.f, p2 = 0.f, p3 = 0.f;
    const uint32_t* clane = &lds[4096 + 8 * sub];
#pragma unroll
    for (int n = 0; n < kN; ++n) {
        const uint32_t hp0 = pack_f16(hA[n].x, hA[n].y);
        const uint32_t hp1 = pack_f16(hB[n].x, hB[n].y);
        const uint4 cv0 = *(const uint4*)&clane[n * 128];      // j=2sub,   c=0..3
        const uint4 cv1 = *(const uint4*)&clane[n * 128 + 4];  // j=2sub+1, c=0..3
        p0 = fdot2(hp0, cv0.x, p0); p0 = fdot2(hp1, cv1.x, p0);
        p1 = fdot2(hp0, cv0.y, p1); p1 = fdot2(hp1, cv1.y, p1);
        p2 = fdot2(hp0, cv0.z, p2); p2 = fdot2(hp1, cv1.z, p2);
        p3 = fdot2(hp0, cv0.w, p3); p3 = fdot2(hp1, cv1.w, p3);
    }
    p0 = rowSum16(p0);
    p1 = rowSum16(p1);
    p2 = rowSum16(p2);
    p3 = rowSum16(p3);

    if (sub == 0) {
        const float4 cbv = *(const float4*)cls_b;
        *(float4*)&out[b * 4] = make_float4(p0 + cbv.x, p1 + cbv.y,
                                            p2 + cbv.z, p3 + cbv.w);
    }
}

} // namespace

extern "C" void kernel_launch(void* const* d_in, const int* in_sizes, int n_in,
                              void* d_out, int out_size, void* d_ws, size_t ws_size,
                              hipStream_t stream)
{
    const float* x      = (const float*)d_in[0];
    const float* mp_w   = (const float*)d_in[1];
    const float* mp_b   = (const float*)d_in[2];
    const float* attn_w = (const float*)d_in[3];
    // d_in[4] = attn_b : cancels in softmax, unused
    const float* ln_g   = (const float*)d_in[5];
    const float* ln_b   = (const float*)d_in[6];
    const float* cls_w  = (const float*)d_in[7];
    const float* cls_b  = (const float*)d_in[8];
    float* out = (float*)d_out;

    gnn_fused<<<GRID, BLOCK, 0, stream>>>(x, mp_w, mp_b, attn_w,
                                          ln_g, ln_b, cls_w, cls_b, out);
}